// Round 6
// baseline (580.301 us; speedup 1.0000x reference)
//
#include <hip/hip_runtime.h>

#define NN 50000
#define NE 800000
#define ND 64
#define ED 32
#define HID 64
#define NL 2
#define IN_MSG 96   // ND + ED
#define IN_UPD 128  // ND + HID

#define W1_LD 104   // ushort stride for W1^T rows (96+8), 208B
#define H_LD 72     // ushort stride for h rows (64+8), 144B
#define MSG_LD 72   // ushort stride for msg staging rows, 144B (16B-aligned)
#define UPD_LD 136  // ushort stride for node comb rows (128+8), 272B

#define NBLK 768            // 3 blocks/CU x 256 CUs
#define WPB 4
#define TOTW (NBLK * WPB)   // 3072 waves
#define NGRP (NE / 32)      // 25000 groups of 32 edges

typedef __attribute__((ext_vector_type(8))) short short8;  // 8 bf16 = 4 VGPR
typedef __attribute__((ext_vector_type(4))) float f32x4;

__device__ inline ushort bf16r(float f) {  // fp32 -> bf16, RNE
    union { float f; unsigned u; } x; x.f = f;
    return (ushort)((x.u + 0x7FFFu + ((x.u >> 16) & 1u)) >> 16);
}
__device__ inline float b2f(unsigned u) {
    union { unsigned u; float f; } x; x.u = u << 16; return x.f;
}
__device__ inline short8 pk8(float4 a, float4 b) {
    short8 r;
    r[0] = (short)bf16r(a.x); r[1] = (short)bf16r(a.y);
    r[2] = (short)bf16r(a.z); r[3] = (short)bf16r(a.w);
    r[4] = (short)bf16r(b.x); r[5] = (short)bf16r(b.y);
    r[6] = (short)bf16r(b.z); r[7] = (short)bf16r(b.w);
    return r;
}
__device__ inline uint2 pack4(float4 v) {
    return make_uint2((unsigned)bf16r(v.x) | ((unsigned)bf16r(v.y) << 16),
                      (unsigned)bf16r(v.z) | ((unsigned)bf16r(v.w) << 16));
}

// ============================ CSR build =====================================
__global__ __launch_bounds__(256) void hist_kernel(const int* __restrict__ dst,
                                                   int* __restrict__ cnt)
{
    const int i = blockIdx.x * 256 + threadIdx.x;   // grid exact: 3125*256 = NE
    atomicAdd(&cnt[dst[i]], 1);
}

__global__ __launch_bounds__(1024) void scan_kernel(int* __restrict__ cnt,   // in: counts, out: cursor
                                                    int* __restrict__ off)
{
    __shared__ int part[1024];
    const int t = threadIdx.x;
    const int base = t * 49;
    int s = 0;
    for (int i = 0; i < 49; ++i) {
        const int idx = base + i;
        if (idx < NN) s += cnt[idx];
    }
    part[t] = s;
    __syncthreads();
    for (int d = 1; d < 1024; d <<= 1) {
        const int v = (t >= d) ? part[t - d] : 0;
        __syncthreads();
        part[t] += v;
        __syncthreads();
    }
    int run = (t == 0) ? 0 : part[t - 1];
    for (int i = 0; i < 49; ++i) {
        const int idx = base + i;
        if (idx < NN) {
            const int c = cnt[idx];
            off[idx] = run;
            cnt[idx] = run;   // cursor copy (in place)
            run += c;
        }
    }
    if (t == 1023) off[NN] = NE;
}

__global__ __launch_bounds__(256) void fill_kernel(const int* __restrict__ dst,
                                                   int* __restrict__ cursor,
                                                   int* __restrict__ perm)
{
    const int i = blockIdx.x * 256 + threadIdx.x;   // grid exact
    const int pos = atomicAdd(&cursor[dst[i]], 1);
    perm[pos] = i;
}

// ======================= edge message MLP (MFMA) ============================
// CSR=1: write bf16 messages to msgbuf (coalesced, edge order).
// CSR=0: fallback — direct C-frag atomics into agg/deg (round-5 path).
template <int CSR>
__global__ __launch_bounds__(256, 3)
void msg_kernel(const float* __restrict__ nf,
                const float* __restrict__ ef,
                const float* __restrict__ w1,
                const float* __restrict__ b1,
                const float* __restrict__ w2,
                const float* __restrict__ b2,
                const int* __restrict__ src,
                const int* __restrict__ dst,
                ushort* __restrict__ msgbuf,
                float* __restrict__ agg,
                float* __restrict__ deg)
{
    __shared__ __align__(16) ushort sW1t[NL][64][W1_LD];   // 26,624 B
    __shared__ __align__(16) ushort sH[WPB][16][H_LD];     //  9,216 B
    __shared__ __align__(16) ushort sMsg[WPB][32][MSG_LD]; // 18,432 B => 54,272 B

    const int tid = threadIdx.x;
    const int w  = tid >> 6;
    const int l  = tid & 63;
    const int lr = l & 15;
    const int lg = l >> 4;

    // ---- one-time stage: W1^T (padded) ----
    {
        const int k16 = tid >> 4, n0 = (tid & 15) * 4;
        #pragma unroll
        for (int lay = 0; lay < NL; ++lay)
            #pragma unroll
            for (int it = 0; it < 6; ++it) {
                const int k = k16 + 16 * it;   // 0..95
                const float4 v = *reinterpret_cast<const float4*>(
                    w1 + ((size_t)lay * IN_MSG + k) * HID + n0);
                sW1t[lay][n0 + 0][k] = bf16r(v.x);
                sW1t[lay][n0 + 1][k] = bf16r(v.y);
                sW1t[lay][n0 + 2][k] = bf16r(v.z);
                sW1t[lay][n0 + 3][k] = bf16r(v.w);
            }
    }
    // ---- W2 B-fragments in registers (both layers) ----
    short8 w2f[NL][4][2];
    #pragma unroll
    for (int lay = 0; lay < NL; ++lay)
        #pragma unroll
        for (int nt = 0; nt < 4; ++nt)
            #pragma unroll
            for (int ks = 0; ks < 2; ++ks) {
                short8 t;
                #pragma unroll
                for (int j = 0; j < 8; ++j)
                    t[j] = (short)bf16r(
                        w2[((size_t)lay * HID + ks * 32 + 8 * lg + j) * HID + nt * 16 + lr]);
                w2f[lay][nt][ks] = t;
            }
    // ---- biases in registers ----
    float bias1[NL][4], bias2s[4];
    #pragma unroll
    for (int lay = 0; lay < NL; ++lay)
        #pragma unroll
        for (int nt = 0; nt < 4; ++nt)
            bias1[lay][nt] = b1[lay * HID + nt * 16 + lr];
    #pragma unroll
    for (int nt = 0; nt < 4; ++nt)
        bias2s[nt] = b2[nt * 16 + lr] + b2[HID + nt * 16 + lr];
    __syncthreads();

    const float4* nfr = reinterpret_cast<const float4*>(nf);  // 16 float4 / row
    const float4* efr = reinterpret_cast<const float4*>(ef);  //  8 float4 / row

    // ---- prologue ----
    int g = blockIdx.x * WPB + w;
    int srcv = 0, dstv = 0, srcn = 0, dstn = 0;
    if (l < 32) {
        srcv = src[(size_t)g * 32 + l];
        if (!CSR) dstv = dst[(size_t)g * 32 + l];
    }
    {
        const int gn = g + TOTW;
        if (gn < NGRP && l < 32) {
            srcn = src[(size_t)gn * 32 + l];
            if (!CSR) dstn = dst[(size_t)gn * 32 + l];
        }
    }
    float4 nfv[2][4], efv[2][2];
    #pragma unroll
    for (int mt = 0; mt < 2; ++mt) {
        const int s = __shfl(srcv, mt * 16 + lr);
        const float4* p = nfr + (size_t)s * 16;
        nfv[mt][0] = p[2 * lg];     nfv[mt][1] = p[2 * lg + 1];
        nfv[mt][2] = p[8 + 2 * lg]; nfv[mt][3] = p[9 + 2 * lg];
        const float4* q = efr + (size_t)(g * 32 + mt * 16 + lr) * 8;
        efv[mt][0] = q[2 * lg];     efv[mt][1] = q[2 * lg + 1];
    }

    #pragma unroll 1
    while (g < NGRP) {
        const int gn  = g + TOTW;
        const int gnn = g + 2 * TOTW;
        const bool more = (gn < NGRP);

        short8 cmbA[2][3];
        #pragma unroll
        for (int mt = 0; mt < 2; ++mt) {
            cmbA[mt][0] = pk8(nfv[mt][0], nfv[mt][1]);
            cmbA[mt][1] = pk8(nfv[mt][2], nfv[mt][3]);
            cmbA[mt][2] = pk8(efv[mt][0], efv[mt][1]);
        }

        int srcn2 = 0, dstn2 = 0;
        if (gnn < NGRP && l < 32) {
            srcn2 = src[(size_t)gnn * 32 + l];
            if (!CSR) dstn2 = dst[(size_t)gnn * 32 + l];
        }
        float4 nfn[2][4], efn[2][2];
        if (more) {
            #pragma unroll
            for (int mt = 0; mt < 2; ++mt) {
                const float4* q = efr + (size_t)(gn * 32 + mt * 16 + lr) * 8;
                efn[mt][0] = q[2 * lg]; efn[mt][1] = q[2 * lg + 1];
            }
        }

        f32x4 msg[2][4];
        #pragma unroll
        for (int nt = 0; nt < 4; ++nt) {
            const float v = bias2s[nt];
            msg[0][nt] = (f32x4){v, v, v, v};
            msg[1][nt] = (f32x4){v, v, v, v};
        }

        #pragma unroll
        for (int lay = 0; lay < NL; ++lay) {
            #pragma unroll
            for (int mt = 0; mt < 2; ++mt) {
                f32x4 acc[4];
                #pragma unroll
                for (int nt = 0; nt < 4; ++nt) {
                    const float bv = bias1[lay][nt];
                    acc[nt] = (f32x4){bv, bv, bv, bv};
                }
                __builtin_amdgcn_s_setprio(1);
                #pragma unroll
                for (int ks = 0; ks < 3; ++ks)
                    #pragma unroll
                    for (int nt = 0; nt < 4; ++nt) {
                        const short8 B = *reinterpret_cast<const short8*>(
                            &sW1t[lay][nt * 16 + lr][ks * 32 + 8 * lg]);
                        acc[nt] = __builtin_amdgcn_mfma_f32_16x16x32_bf16(
                            cmbA[mt][ks], B, acc[nt], 0, 0, 0);
                    }
                __builtin_amdgcn_s_setprio(0);
                #pragma unroll
                for (int nt = 0; nt < 4; ++nt)
                    #pragma unroll
                    for (int r = 0; r < 4; ++r)
                        sH[w][4 * lg + r][nt * 16 + lr] = bf16r(fmaxf(acc[nt][r], 0.0f));
                const short8 h0 = *reinterpret_cast<const short8*>(&sH[w][lr][ 0 + 8 * lg]);
                const short8 h1 = *reinterpret_cast<const short8*>(&sH[w][lr][32 + 8 * lg]);
                __builtin_amdgcn_s_setprio(1);
                #pragma unroll
                for (int nt = 0; nt < 4; ++nt) {
                    msg[mt][nt] = __builtin_amdgcn_mfma_f32_16x16x32_bf16(h0, w2f[lay][nt][0], msg[mt][nt], 0, 0, 0);
                    msg[mt][nt] = __builtin_amdgcn_mfma_f32_16x16x32_bf16(h1, w2f[lay][nt][1], msg[mt][nt], 0, 0, 0);
                }
                __builtin_amdgcn_s_setprio(0);
            }
            if (lay == 0 && more) {
                #pragma unroll
                for (int mt = 0; mt < 2; ++mt) {
                    const int s = __shfl(srcn, mt * 16 + lr);
                    const float4* p = nfr + (size_t)s * 16;
                    nfn[mt][0] = p[2 * lg];     nfn[mt][1] = p[2 * lg + 1];
                    nfn[mt][2] = p[8 + 2 * lg]; nfn[mt][3] = p[9 + 2 * lg];
                }
            }
        }

        if (CSR) {
            // ---- flush: LDS transpose -> coalesced bf16 rows in edge order ----
            #pragma unroll
            for (int mt = 0; mt < 2; ++mt)
                #pragma unroll
                for (int nt = 0; nt < 4; ++nt)
                    #pragma unroll
                    for (int r = 0; r < 4; ++r)
                        sMsg[w][mt * 16 + 4 * lg + r][nt * 16 + lr] = bf16r(msg[mt][nt][r]);
            #pragma unroll
            for (int it = 0; it < 4; ++it) {
                const int row = (l >> 3) + 8 * it;
                const int c8  = l & 7;
                const short8 v = *reinterpret_cast<const short8*>(&sMsg[w][row][c8 * 8]);
                *reinterpret_cast<short8*>(msgbuf + ((size_t)(g * 32 + row)) * 64 + c8 * 8) = v;
            }
        } else {
            #pragma unroll
            for (int mt = 0; mt < 2; ++mt)
                #pragma unroll
                for (int r = 0; r < 4; ++r) {
                    const int drow = __shfl(dstv, mt * 16 + 4 * lg + r);
                    float* rowp = agg + (size_t)drow * HID;
                    #pragma unroll
                    for (int nt = 0; nt < 4; ++nt)
                        atomicAdd(rowp + nt * 16 + lr, msg[mt][nt][r]);
                }
            if (l < 32) atomicAdd(&deg[dstv], 1.0f);
        }

        srcv = srcn; dstv = dstn; srcn = srcn2; dstn = dstn2;
        #pragma unroll
        for (int mt = 0; mt < 2; ++mt) {
            #pragma unroll
            for (int i = 0; i < 4; ++i) nfv[mt][i] = nfn[mt][i];
            efv[mt][0] = efn[mt][0]; efv[mt][1] = efn[mt][1];
        }
        g = gn;
    }
}

// ================== fused CSR gather + node update (MFMA) ===================
__global__ __launch_bounds__(256, 2)
void upd_csr_kernel(const float* __restrict__ nf,
                    const ushort* __restrict__ msgbuf,
                    const int* __restrict__ perm,
                    const int* __restrict__ off,
                    const float* __restrict__ uw1,
                    const float* __restrict__ ub1,
                    const float* __restrict__ uw2,
                    const float* __restrict__ ub2,
                    float* __restrict__ out)
{
    __shared__ __align__(16) ushort sAct[WPB][32][UPD_LD];
    __shared__ __align__(16) ushort sW1t[64][UPD_LD];
    __shared__ __align__(16) ushort sW2t[64][H_LD];
    __shared__ float sUB1[64], sUB2[64];

    const int tid = threadIdx.x;
    const int w  = tid >> 6;
    const int l  = tid & 63;
    const int lr = l & 15;
    const int lg = l >> 4;

    {   // weight stage
        const int k16 = tid >> 4, n0 = (tid & 15) * 4;
        #pragma unroll
        for (int it = 0; it < 8; ++it) {
            const int k = k16 + 16 * it;    // 0..127
            const float4 v = *reinterpret_cast<const float4*>(uw1 + (size_t)k * HID + n0);
            sW1t[n0 + 0][k] = bf16r(v.x);
            sW1t[n0 + 1][k] = bf16r(v.y);
            sW1t[n0 + 2][k] = bf16r(v.z);
            sW1t[n0 + 3][k] = bf16r(v.w);
        }
        #pragma unroll
        for (int it = 0; it < 4; ++it) {
            const int k = k16 + 16 * it;    // 0..63
            const float4 v = *reinterpret_cast<const float4*>(uw2 + (size_t)k * ND + n0);
            sW2t[n0 + 0][k] = bf16r(v.x);
            sW2t[n0 + 1][k] = bf16r(v.y);
            sW2t[n0 + 2][k] = bf16r(v.z);
            sW2t[n0 + 3][k] = bf16r(v.w);
        }
        if (tid < 64) { sUB1[tid] = ub1[tid]; sUB2[tid] = ub2[tid]; }
    }

    const int nbase = blockIdx.x * 128 + w * 32;

    // ---- stage node features (bf16) ----
    #pragma unroll
    for (int it = 0; it < 8; ++it) {
        const int row = lg + 4 * it;
        const int n = min(nbase + row, NN - 1);
        const float4 v = reinterpret_cast<const float4*>(nf + (size_t)n * ND)[lr];
        *reinterpret_cast<uint2*>(&sAct[w][row][lr * 4]) = pack4(v);
    }

    // ---- CSR gather: quarter-wave per node, lane owns 4 columns ----
    {
        const int q  = l >> 4;     // quarter id 0..3
        const int ql = l & 15;     // lane in quarter
        #pragma unroll 1
        for (int it = 0; it < 8; ++it) {
            const int nrow = q + 4 * it;           // 0..31
            const int n = min(nbase + nrow, NN - 1);
            const int o0 = off[n];
            const int degn = off[n + 1] - o0;
            float a0 = 0.f, a1 = 0.f, a2 = 0.f, a3 = 0.f;
            #pragma unroll 1
            for (int base = 0; base < degn; base += 16) {
                const int rem = degn - base;
                int pe = 0;
                if (ql < rem) pe = perm[o0 + base + ql];
                if (rem >= 16) {
                    #pragma unroll
                    for (int j = 0; j < 16; ++j) {
                        const int e = __shfl(pe, q * 16 + j);
                        const uint2 mv = *reinterpret_cast<const uint2*>(
                            msgbuf + (size_t)e * 64 + ql * 4);
                        a0 += b2f(mv.x & 0xffffu); a1 += b2f(mv.x >> 16);
                        a2 += b2f(mv.y & 0xffffu); a3 += b2f(mv.y >> 16);
                    }
                } else {
                    #pragma unroll 1
                    for (int j = 0; j < rem; ++j) {
                        const int e = __shfl(pe, q * 16 + j);
                        const uint2 mv = *reinterpret_cast<const uint2*>(
                            msgbuf + (size_t)e * 64 + ql * 4);
                        a0 += b2f(mv.x & 0xffffu); a1 += b2f(mv.x >> 16);
                        a2 += b2f(mv.y & 0xffffu); a3 += b2f(mv.y >> 16);
                    }
                }
            }
            const float invd = 1.0f / ((float)degn + 1e-8f);
            const float4 av = make_float4(a0 * invd, a1 * invd, a2 * invd, a3 * invd);
            *reinterpret_cast<uint2*>(&sAct[w][nrow][ND + ql * 4]) = pack4(av);
        }
    }
    __syncthreads();

    // ---- GEMM1: K=128 ----
    short8 A[2][4];
    #pragma unroll
    for (int mt = 0; mt < 2; ++mt)
        #pragma unroll
        for (int ks = 0; ks < 4; ++ks)
            A[mt][ks] = *reinterpret_cast<const short8*>(&sAct[w][mt * 16 + lr][ks * 32 + 8 * lg]);
    #pragma unroll
    for (int nt = 0; nt < 4; ++nt) {
        const int cB = nt * 16 + lr;
        short8 B[4];
        #pragma unroll
        for (int ks = 0; ks < 4; ++ks)
            B[ks] = *reinterpret_cast<const short8*>(&sW1t[cB][ks * 32 + 8 * lg]);
        const float bv = sUB1[cB];
        #pragma unroll
        for (int mt = 0; mt < 2; ++mt) {
            f32x4 acc = (f32x4){bv, bv, bv, bv};
            #pragma unroll
            for (int ks = 0; ks < 4; ++ks)
                acc = __builtin_amdgcn_mfma_f32_16x16x32_bf16(A[mt][ks], B[ks], acc, 0, 0, 0);
            const int rH = mt * 16 + 4 * lg;
            #pragma unroll
            for (int r = 0; r < 4; ++r)
                sAct[w][rH + r][cB] = bf16r(fmaxf(acc[r], 0.0f));   // h overlays cols 0..63
        }
    }

    // ---- GEMM2: K=64 ----
    f32x4 o[2][4];
    #pragma unroll
    for (int nt = 0; nt < 4; ++nt) {
        const float v = sUB2[nt * 16 + lr];
        o[0][nt] = (f32x4){v, v, v, v};
        o[1][nt] = (f32x4){v, v, v, v};
    }
    #pragma unroll
    for (int mt = 0; mt < 2; ++mt) {
        const short8 A0 = *reinterpret_cast<const short8*>(&sAct[w][mt * 16 + lr][ 0 + 8 * lg]);
        const short8 A1 = *reinterpret_cast<const short8*>(&sAct[w][mt * 16 + lr][32 + 8 * lg]);
        #pragma unroll
        for (int nt = 0; nt < 4; ++nt) {
            const int cB = nt * 16 + lr;
            const short8 B0 = *reinterpret_cast<const short8*>(&sW2t[cB][ 0 + 8 * lg]);
            const short8 B1 = *reinterpret_cast<const short8*>(&sW2t[cB][32 + 8 * lg]);
            o[mt][nt] = __builtin_amdgcn_mfma_f32_16x16x32_bf16(A0, B0, o[mt][nt], 0, 0, 0);
            o[mt][nt] = __builtin_amdgcn_mfma_f32_16x16x32_bf16(A1, B1, o[mt][nt], 0, 0, 0);
        }
    }

    #pragma unroll
    for (int mt = 0; mt < 2; ++mt)
        #pragma unroll
        for (int r = 0; r < 4; ++r) {
            const int n = nbase + mt * 16 + 4 * lg + r;
            if (n < NN) {
                float* rowp = out + (size_t)n * ND;
                #pragma unroll
                for (int nt = 0; nt < 4; ++nt)
                    rowp[nt * 16 + lr] = o[mt][nt][r];
            }
        }
}

// ============== fallback node update (atomic-agg path, round-5) =============
__global__ __launch_bounds__(256, 2)
void node_update_kernel(const float* __restrict__ nf,
                        const float* __restrict__ agg,
                        const float* __restrict__ deg,
                        const float* __restrict__ uw1,
                        const float* __restrict__ ub1,
                        const float* __restrict__ uw2,
                        const float* __restrict__ ub2,
                        float* __restrict__ out)
{
    __shared__ __align__(16) ushort sAct[WPB][32][UPD_LD];
    __shared__ __align__(16) ushort sW1t[64][UPD_LD];
    __shared__ __align__(16) ushort sW2t[64][H_LD];
    __shared__ float sUB1[64], sUB2[64];

    const int tid = threadIdx.x;
    const int w  = tid >> 6;
    const int l  = tid & 63;
    const int lr = l & 15;
    const int lg = l >> 4;

    {
        const int k16 = tid >> 4, n0 = (tid & 15) * 4;
        #pragma unroll
        for (int it = 0; it < 8; ++it) {
            const int k = k16 + 16 * it;
            const float4 v = *reinterpret_cast<const float4*>(uw1 + (size_t)k * HID + n0);
            sW1t[n0 + 0][k] = bf16r(v.x);
            sW1t[n0 + 1][k] = bf16r(v.y);
            sW1t[n0 + 2][k] = bf16r(v.z);
            sW1t[n0 + 3][k] = bf16r(v.w);
        }
        #pragma unroll
        for (int it = 0; it < 4; ++it) {
            const int k = k16 + 16 * it;
            const float4 v = *reinterpret_cast<const float4*>(uw2 + (size_t)k * ND + n0);
            sW2t[n0 + 0][k] = bf16r(v.x);
            sW2t[n0 + 1][k] = bf16r(v.y);
            sW2t[n0 + 2][k] = bf16r(v.z);
            sW2t[n0 + 3][k] = bf16r(v.w);
        }
        if (tid < 64) { sUB1[tid] = ub1[tid]; sUB2[tid] = ub2[tid]; }
    }

    const int nbase = blockIdx.x * 128 + w * 32;
    float invv = 0.0f;
    if (l < 32) invv = 1.0f / (deg[min(nbase + l, NN - 1)] + 1e-8f);

    #pragma unroll
    for (int it = 0; it < 8; ++it) {
        const int row = lg + 4 * it;
        const int n = min(nbase + row, NN - 1);
        const float4 v = reinterpret_cast<const float4*>(nf + (size_t)n * ND)[lr];
        *reinterpret_cast<uint2*>(&sAct[w][row][lr * 4]) = pack4(v);
    }
    #pragma unroll
    for (int it = 0; it < 8; ++it) {
        const int row = lg + 4 * it;
        const int n = min(nbase + row, NN - 1);
        const float iv = __shfl(invv, row);
        float4 v = reinterpret_cast<const float4*>(agg + (size_t)n * HID)[lr];
        v.x *= iv; v.y *= iv; v.z *= iv; v.w *= iv;
        *reinterpret_cast<uint2*>(&sAct[w][row][ND + lr * 4]) = pack4(v);
    }
    __syncthreads();

    short8 A[2][4];
    #pragma unroll
    for (int mt = 0; mt < 2; ++mt)
        #pragma unroll
        for (int ks = 0; ks < 4; ++ks)
            A[mt][ks] = *reinterpret_cast<const short8*>(&sAct[w][mt * 16 + lr][ks * 32 + 8 * lg]);
    #pragma unroll
    for (int nt = 0; nt < 4; ++nt) {
        const int cB = nt * 16 + lr;
        short8 B[4];
        #pragma unroll
        for (int ks = 0; ks < 4; ++ks)
            B[ks] = *reinterpret_cast<const short8*>(&sW1t[cB][ks * 32 + 8 * lg]);
        const float bv = sUB1[cB];
        #pragma unroll
        for (int mt = 0; mt < 2; ++mt) {
            f32x4 acc = (f32x4){bv, bv, bv, bv};
            #pragma unroll
            for (int ks = 0; ks < 4; ++ks)
                acc = __builtin_amdgcn_mfma_f32_16x16x32_bf16(A[mt][ks], B[ks], acc, 0, 0, 0);
            const int rH = mt * 16 + 4 * lg;
            #pragma unroll
            for (int r = 0; r < 4; ++r)
                sAct[w][rH + r][cB] = bf16r(fmaxf(acc[r], 0.0f));
        }
    }

    f32x4 o[2][4];
    #pragma unroll
    for (int nt = 0; nt < 4; ++nt) {
        const float v = sUB2[nt * 16 + lr];
        o[0][nt] = (f32x4){v, v, v, v};
        o[1][nt] = (f32x4){v, v, v, v};
    }
    #pragma unroll
    for (int mt = 0; mt < 2; ++mt) {
        const short8 A0 = *reinterpret_cast<const short8*>(&sAct[w][mt * 16 + lr][ 0 + 8 * lg]);
        const short8 A1 = *reinterpret_cast<const short8*>(&sAct[w][mt * 16 + lr][32 + 8 * lg]);
        #pragma unroll
        for (int nt = 0; nt < 4; ++nt) {
            const int cB = nt * 16 + lr;
            const short8 B0 = *reinterpret_cast<const short8*>(&sW2t[cB][ 0 + 8 * lg]);
            const short8 B1 = *reinterpret_cast<const short8*>(&sW2t[cB][32 + 8 * lg]);
            o[mt][nt] = __builtin_amdgcn_mfma_f32_16x16x32_bf16(A0, B0, o[mt][nt], 0, 0, 0);
            o[mt][nt] = __builtin_amdgcn_mfma_f32_16x16x32_bf16(A1, B1, o[mt][nt], 0, 0, 0);
        }
    }

    #pragma unroll
    for (int mt = 0; mt < 2; ++mt)
        #pragma unroll
        for (int r = 0; r < 4; ++r) {
            const int n = nbase + mt * 16 + 4 * lg + r;
            if (n < NN) {
                float* rowp = out + (size_t)n * ND;
                #pragma unroll
                for (int nt = 0; nt < 4; ++nt)
                    rowp[nt * 16 + lr] = o[mt][nt][r];
            }
        }
}

extern "C" void kernel_launch(void* const* d_in, const int* in_sizes, int n_in,
                              void* d_out, int out_size, void* d_ws, size_t ws_size,
                              hipStream_t stream)
{
    const float* nf  = (const float*)d_in[0];
    const float* ef  = (const float*)d_in[1];
    const float* w1  = (const float*)d_in[2];
    const float* b1  = (const float*)d_in[3];
    const float* w2  = (const float*)d_in[4];
    const float* b2  = (const float*)d_in[5];
    const float* uw1 = (const float*)d_in[6];
    const float* ub1 = (const float*)d_in[7];
    const float* uw2 = (const float*)d_in[8];
    const float* ub2 = (const float*)d_in[9];
    const int*   src = (const int*)d_in[10];
    const int*   dst = (const int*)d_in[11];
    float* out = (float*)d_out;

    constexpr size_t MSGB  = (size_t)NE * 64 * 2;      // 102,400,000
    constexpr size_t PERMB = (size_t)NE * 4;           //   3,200,000
    constexpr size_t OFFB  = (size_t)(NN + 1) * 4;     //     200,004
    constexpr size_t CNTB  = (size_t)NN * 4;           //     200,000
    constexpr size_t NEED  = MSGB + PERMB + OFFB + CNTB;

    if (ws_size >= NEED) {
        ushort* msgbuf = (ushort*)d_ws;
        int* perm = (int*)((char*)d_ws + MSGB);
        int* off  = (int*)((char*)d_ws + MSGB + PERMB);
        int* cnt  = (int*)((char*)d_ws + MSGB + PERMB + OFFB);   // also cursor

        hipMemsetAsync(cnt, 0, CNTB, stream);
        hist_kernel<<<NE / 256, 256, 0, stream>>>(dst, cnt);
        scan_kernel<<<1, 1024, 0, stream>>>(cnt, off);
        fill_kernel<<<NE / 256, 256, 0, stream>>>(dst, cnt, perm);
        msg_kernel<1><<<NBLK, 256, 0, stream>>>(nf, ef, w1, b1, w2, b2, src, dst,
                                                msgbuf, nullptr, nullptr);
        upd_csr_kernel<<<(NN + 127) / 128, 256, 0, stream>>>(nf, msgbuf, perm, off,
                                                             uw1, ub1, uw2, ub2, out);
    } else {
        float* agg = (float*)d_ws;                    // [NN][HID]
        float* deg = agg + (size_t)NN * HID;          // [NN]
        hipMemsetAsync(d_ws, 0, ((size_t)NN * HID + NN) * sizeof(float), stream);
        msg_kernel<0><<<NBLK, 256, 0, stream>>>(nf, ef, w1, b1, w2, b2, src, dst,
                                                nullptr, agg, deg);
        node_update_kernel<<<(NN + 127) / 128, 256, 0, stream>>>(nf, agg, deg,
                                                                 uw1, ub1, uw2, ub2, out);
    }
}

// Round 8
// 430.119 us; speedup vs baseline: 1.3492x; 1.3492x over previous
//
#include <hip/hip_runtime.h>

#define NN 50000
#define NE 800000
#define ND 64
#define ED 32
#define HID 64
#define NL 2
#define IN_MSG 96   // ND + ED
#define IN_UPD 128  // ND + HID

#define W1_LD 104   // ushort stride for W1^T rows (96+8), 208B
#define H_LD 72     // ushort stride for h rows (64+8), 144B
#define MSG_LD 72   // ushort stride for msg staging rows, 144B
#define UPD_LD 136  // ushort stride for node comb rows (128+8), 272B

#define NBLK 768            // 3 blocks/CU x 256 CUs
#define WPB 4
#define TOTW (NBLK * WPB)   // 3072 waves
#define NGRP (NE / 32)      // 25000 groups of 32 edges
#define NB_SCAN 196         // ceil(NN/256)

typedef __attribute__((ext_vector_type(8))) short short8;  // 8 bf16 = 4 VGPR
typedef __attribute__((ext_vector_type(4))) float f32x4;
typedef __attribute__((ext_vector_type(2))) unsigned int u32x2;

__device__ inline ushort bf16r(float f) {  // fp32 -> bf16, RNE
    union { float f; unsigned u; } x; x.f = f;
    return (ushort)((x.u + 0x7FFFu + ((x.u >> 16) & 1u)) >> 16);
}
__device__ inline float b2f(unsigned u) {
    union { unsigned u; float f; } x; x.u = u << 16; return x.f;
}
__device__ inline float4 ntl_f4(const float4* p) {   // nontemporal float4 load
    const f32x4 v = __builtin_nontemporal_load(reinterpret_cast<const f32x4*>(p));
    return make_float4(v[0], v[1], v[2], v[3]);
}
__device__ inline short8 pk8(float4 a, float4 b) {
    short8 r;
    r[0] = (short)bf16r(a.x); r[1] = (short)bf16r(a.y);
    r[2] = (short)bf16r(a.z); r[3] = (short)bf16r(a.w);
    r[4] = (short)bf16r(b.x); r[5] = (short)bf16r(b.y);
    r[6] = (short)bf16r(b.z); r[7] = (short)bf16r(b.w);
    return r;
}
__device__ inline uint2 pack4(float4 v) {
    return make_uint2((unsigned)bf16r(v.x) | ((unsigned)bf16r(v.y) << 16),
                      (unsigned)bf16r(v.z) | ((unsigned)bf16r(v.w) << 16));
}

// ============================ CSR build =====================================
__global__ __launch_bounds__(256) void hist_kernel(const int* __restrict__ dst,
                                                   int* __restrict__ cnt)
{
    const int i = blockIdx.x * 256 + threadIdx.x;   // grid exact
    atomicAdd(&cnt[dst[i]], 1);
}

// per-block exclusive scan of cnt -> off ; block total -> bsum[b]
__global__ __launch_bounds__(256) void scanA_kernel(const int* __restrict__ cnt,
                                                    int* __restrict__ off,
                                                    int* __restrict__ bsum)
{
    __shared__ int buf[256];
    const int t = threadIdx.x;
    const int i = blockIdx.x * 256 + t;
    const int v = (i < NN) ? cnt[i] : 0;
    buf[t] = v;
    __syncthreads();
    #pragma unroll
    for (int d = 1; d < 256; d <<= 1) {
        const int x = (t >= d) ? buf[t - d] : 0;
        __syncthreads();
        buf[t] += x;
        __syncthreads();
    }
    if (i < NN) off[i] = buf[t] - v;          // exclusive within block
    if (t == 255) bsum[blockIdx.x] = buf[255];
}

// inclusive scan of the 196 block sums (in place)
__global__ __launch_bounds__(256) void scanB_kernel(int* __restrict__ bsum)
{
    __shared__ int buf[256];
    const int t = threadIdx.x;
    buf[t] = (t < NB_SCAN) ? bsum[t] : 0;
    __syncthreads();
    #pragma unroll
    for (int d = 1; d < 256; d <<= 1) {
        const int x = (t >= d) ? buf[t - d] : 0;
        __syncthreads();
        buf[t] += x;
        __syncthreads();
    }
    if (t < NB_SCAN) bsum[t] = buf[t];
}

// add block offsets; copy to cursor; finalize off[NN]
__global__ __launch_bounds__(256) void scanC_kernel(const int* __restrict__ bsum,
                                                    int* __restrict__ off,
                                                    int* __restrict__ cursor)
{
    const int b = blockIdx.x;
    const int i = b * 256 + threadIdx.x;
    const int boff = (b > 0) ? bsum[b - 1] : 0;
    if (i < NN) {
        const int e = off[i] + boff;
        off[i] = e;
        cursor[i] = e;
    }
    if (i == 0) off[NN] = NE;
}

__global__ __launch_bounds__(256) void fill_kernel(const int* __restrict__ dst,
                                                   int* __restrict__ cursor,
                                                   int* __restrict__ perm)
{
    const int i = blockIdx.x * 256 + threadIdx.x;   // grid exact
    const int pos = atomicAdd(&cursor[dst[i]], 1);
    perm[pos] = i;
}

// ======================= edge message MLP (MFMA) ============================
// CSR=1: nt-write bf16 messages to msgbuf (coalesced, edge order).
// CSR=0: fallback — direct C-frag atomics into agg/deg.
template <int CSR>
__global__ __launch_bounds__(256, 3)
void msg_kernel(const float* __restrict__ nf,
                const float* __restrict__ ef,
                const float* __restrict__ w1,
                const float* __restrict__ b1,
                const float* __restrict__ w2,
                const float* __restrict__ b2,
                const int* __restrict__ src,
                const int* __restrict__ dst,
                ushort* __restrict__ msgbuf,
                float* __restrict__ agg,
                float* __restrict__ deg)
{
    __shared__ __align__(16) ushort sW1t[NL][64][W1_LD];   // 26,624 B
    __shared__ __align__(16) ushort sH[WPB][16][H_LD];     //  9,216 B
    __shared__ __align__(16) ushort sMsg[WPB][32][MSG_LD]; // 18,432 B => 54,272 B

    const int tid = threadIdx.x;
    const int w  = tid >> 6;
    const int l  = tid & 63;
    const int lr = l & 15;
    const int lg = l >> 4;

    // ---- one-time stage: W1^T (padded) ----
    {
        const int k16 = tid >> 4, n0 = (tid & 15) * 4;
        #pragma unroll
        for (int lay = 0; lay < NL; ++lay)
            #pragma unroll
            for (int it = 0; it < 6; ++it) {
                const int k = k16 + 16 * it;   // 0..95
                const float4 v = *reinterpret_cast<const float4*>(
                    w1 + ((size_t)lay * IN_MSG + k) * HID + n0);
                sW1t[lay][n0 + 0][k] = bf16r(v.x);
                sW1t[lay][n0 + 1][k] = bf16r(v.y);
                sW1t[lay][n0 + 2][k] = bf16r(v.z);
                sW1t[lay][n0 + 3][k] = bf16r(v.w);
            }
    }
    // ---- W2 B-fragments in registers (both layers) ----
    short8 w2f[NL][4][2];
    #pragma unroll
    for (int lay = 0; lay < NL; ++lay)
        #pragma unroll
        for (int nt = 0; nt < 4; ++nt)
            #pragma unroll
            for (int ks = 0; ks < 2; ++ks) {
                short8 t;
                #pragma unroll
                for (int j = 0; j < 8; ++j)
                    t[j] = (short)bf16r(
                        w2[((size_t)lay * HID + ks * 32 + 8 * lg + j) * HID + nt * 16 + lr]);
                w2f[lay][nt][ks] = t;
            }
    // ---- biases in registers ----
    float bias1[NL][4], bias2s[4];
    #pragma unroll
    for (int lay = 0; lay < NL; ++lay)
        #pragma unroll
        for (int nt = 0; nt < 4; ++nt)
            bias1[lay][nt] = b1[lay * HID + nt * 16 + lr];
    #pragma unroll
    for (int nt = 0; nt < 4; ++nt)
        bias2s[nt] = b2[nt * 16 + lr] + b2[HID + nt * 16 + lr];
    __syncthreads();

    const float4* nfr = reinterpret_cast<const float4*>(nf);  // 16 float4 / row
    const float4* efr = reinterpret_cast<const float4*>(ef);  //  8 float4 / row

    // ---- prologue ----
    int g = blockIdx.x * WPB + w;
    int srcv = 0, dstv = 0, srcn = 0, dstn = 0;
    if (l < 32) {
        srcv = src[(size_t)g * 32 + l];
        if (!CSR) dstv = dst[(size_t)g * 32 + l];
    }
    {
        const int gn = g + TOTW;
        if (gn < NGRP && l < 32) {
            srcn = src[(size_t)gn * 32 + l];
            if (!CSR) dstn = dst[(size_t)gn * 32 + l];
        }
    }
    float4 nfv[2][4], efv[2][2];
    #pragma unroll
    for (int mt = 0; mt < 2; ++mt) {
        const int s = __shfl(srcv, mt * 16 + lr);
        const float4* p = nfr + (size_t)s * 16;
        nfv[mt][0] = p[2 * lg];     nfv[mt][1] = p[2 * lg + 1];
        nfv[mt][2] = p[8 + 2 * lg]; nfv[mt][3] = p[9 + 2 * lg];
        const float4* q = efr + (size_t)(g * 32 + mt * 16 + lr) * 8;
        efv[mt][0] = ntl_f4(q + 2 * lg);
        efv[mt][1] = ntl_f4(q + 2 * lg + 1);
    }

    #pragma unroll 1
    while (g < NGRP) {
        const int gn  = g + TOTW;
        const int gnn = g + 2 * TOTW;
        const bool more = (gn < NGRP);

        short8 cmbA[2][3];
        #pragma unroll
        for (int mt = 0; mt < 2; ++mt) {
            cmbA[mt][0] = pk8(nfv[mt][0], nfv[mt][1]);
            cmbA[mt][1] = pk8(nfv[mt][2], nfv[mt][3]);
            cmbA[mt][2] = pk8(efv[mt][0], efv[mt][1]);
        }

        int srcn2 = 0, dstn2 = 0;
        if (gnn < NGRP && l < 32) {
            srcn2 = src[(size_t)gnn * 32 + l];
            if (!CSR) dstn2 = dst[(size_t)gnn * 32 + l];
        }
        float4 nfn[2][4], efn[2][2];
        if (more) {
            #pragma unroll
            for (int mt = 0; mt < 2; ++mt) {
                const float4* q = efr + (size_t)(gn * 32 + mt * 16 + lr) * 8;
                efn[mt][0] = ntl_f4(q + 2 * lg);
                efn[mt][1] = ntl_f4(q + 2 * lg + 1);
            }
        }

        f32x4 msg[2][4];
        #pragma unroll
        for (int nt = 0; nt < 4; ++nt) {
            const float v = bias2s[nt];
            msg[0][nt] = (f32x4){v, v, v, v};
            msg[1][nt] = (f32x4){v, v, v, v};
        }

        #pragma unroll
        for (int lay = 0; lay < NL; ++lay) {
            #pragma unroll
            for (int mt = 0; mt < 2; ++mt) {
                f32x4 acc[4];
                #pragma unroll
                for (int nt = 0; nt < 4; ++nt) {
                    const float bv = bias1[lay][nt];
                    acc[nt] = (f32x4){bv, bv, bv, bv};
                }
                __builtin_amdgcn_s_setprio(1);
                #pragma unroll
                for (int ks = 0; ks < 3; ++ks)
                    #pragma unroll
                    for (int nt = 0; nt < 4; ++nt) {
                        const short8 B = *reinterpret_cast<const short8*>(
                            &sW1t[lay][nt * 16 + lr][ks * 32 + 8 * lg]);
                        acc[nt] = __builtin_amdgcn_mfma_f32_16x16x32_bf16(
                            cmbA[mt][ks], B, acc[nt], 0, 0, 0);
                    }
                __builtin_amdgcn_s_setprio(0);
                #pragma unroll
                for (int nt = 0; nt < 4; ++nt)
                    #pragma unroll
                    for (int r = 0; r < 4; ++r)
                        sH[w][4 * lg + r][nt * 16 + lr] = bf16r(fmaxf(acc[nt][r], 0.0f));
                const short8 h0 = *reinterpret_cast<const short8*>(&sH[w][lr][ 0 + 8 * lg]);
                const short8 h1 = *reinterpret_cast<const short8*>(&sH[w][lr][32 + 8 * lg]);
                __builtin_amdgcn_s_setprio(1);
                #pragma unroll
                for (int nt = 0; nt < 4; ++nt) {
                    msg[mt][nt] = __builtin_amdgcn_mfma_f32_16x16x32_bf16(h0, w2f[lay][nt][0], msg[mt][nt], 0, 0, 0);
                    msg[mt][nt] = __builtin_amdgcn_mfma_f32_16x16x32_bf16(h1, w2f[lay][nt][1], msg[mt][nt], 0, 0, 0);
                }
                __builtin_amdgcn_s_setprio(0);
            }
            if (lay == 0 && more) {
                #pragma unroll
                for (int mt = 0; mt < 2; ++mt) {
                    const int s = __shfl(srcn, mt * 16 + lr);
                    const float4* p = nfr + (size_t)s * 16;
                    nfn[mt][0] = p[2 * lg];     nfn[mt][1] = p[2 * lg + 1];
                    nfn[mt][2] = p[8 + 2 * lg]; nfn[mt][3] = p[9 + 2 * lg];
                }
            }
        }

        if (CSR) {
            // ---- flush: LDS transpose -> nt-store coalesced bf16 rows ----
            #pragma unroll
            for (int mt = 0; mt < 2; ++mt)
                #pragma unroll
                for (int nt = 0; nt < 4; ++nt)
                    #pragma unroll
                    for (int r = 0; r < 4; ++r)
                        sMsg[w][mt * 16 + 4 * lg + r][nt * 16 + lr] = bf16r(msg[mt][nt][r]);
            #pragma unroll
            for (int it = 0; it < 4; ++it) {
                const int row = (l >> 3) + 8 * it;
                const int c8  = l & 7;
                const short8 v = *reinterpret_cast<const short8*>(&sMsg[w][row][c8 * 8]);
                __builtin_nontemporal_store(v, reinterpret_cast<short8*>(
                    msgbuf + ((size_t)(g * 32 + row)) * 64 + c8 * 8));
            }
        } else {
            #pragma unroll
            for (int mt = 0; mt < 2; ++mt)
                #pragma unroll
                for (int r = 0; r < 4; ++r) {
                    const int drow = __shfl(dstv, mt * 16 + 4 * lg + r);
                    float* rowp = agg + (size_t)drow * HID;
                    #pragma unroll
                    for (int nt = 0; nt < 4; ++nt)
                        atomicAdd(rowp + nt * 16 + lr, msg[mt][nt][r]);
                }
            if (l < 32) atomicAdd(&deg[dstv], 1.0f);
        }

        srcv = srcn; dstv = dstn; srcn = srcn2; dstn = dstn2;
        #pragma unroll
        for (int mt = 0; mt < 2; ++mt) {
            #pragma unroll
            for (int i = 0; i < 4; ++i) nfv[mt][i] = nfn[mt][i];
            efv[mt][0] = efn[mt][0]; efv[mt][1] = efn[mt][1];
        }
        g = gn;
    }
}

// ================== CSR gather: one node per quarter-wave ===================
// Writes NORMALIZED aggregate rows into aggout (= d_out, block-disjoint rows).
__global__ __launch_bounds__(256)
void gather_kernel(const ushort* __restrict__ msgbuf,
                   const int* __restrict__ perm,
                   const int* __restrict__ off,
                   float* __restrict__ aggout)
{
    const int tid  = threadIdx.x;
    const int node = blockIdx.x * 16 + (tid >> 4);   // 3125*16 = 50000 exact
    const int ql   = tid & 15;
    const int qb   = ((tid >> 4) & 3) * 16;          // quarter's base lane in wave

    const int o0 = off[node];
    const int o1 = off[node + 1];
    float a0 = 0.f, a1 = 0.f, a2 = 0.f, a3 = 0.f;

    #pragma unroll 1
    for (int base = o0; base < o1; base += 16) {
        const int rem = o1 - base;
        int pe = 0;
        if (ql < rem) pe = perm[base + ql];
        if (rem >= 16) {
            #pragma unroll
            for (int j = 0; j < 16; ++j) {
                const int e = __shfl(pe, qb + j);
                const u32x2 mv = __builtin_nontemporal_load(
                    reinterpret_cast<const u32x2*>(msgbuf + (size_t)e * 64 + ql * 4));
                a0 += b2f(mv.x & 0xffffu); a1 += b2f(mv.x >> 16);
                a2 += b2f(mv.y & 0xffffu); a3 += b2f(mv.y >> 16);
            }
        } else {
            #pragma unroll 1
            for (int j = 0; j < rem; ++j) {
                const int e = __shfl(pe, qb + j);
                const u32x2 mv = __builtin_nontemporal_load(
                    reinterpret_cast<const u32x2*>(msgbuf + (size_t)e * 64 + ql * 4));
                a0 += b2f(mv.x & 0xffffu); a1 += b2f(mv.x >> 16);
                a2 += b2f(mv.y & 0xffffu); a3 += b2f(mv.y >> 16);
            }
        }
    }
    const float invd = 1.0f / ((float)(o1 - o0) + 1e-8f);
    const float4 r = make_float4(a0 * invd, a1 * invd, a2 * invd, a3 * invd);
    *reinterpret_cast<float4*>(aggout + (size_t)node * HID + ql * 4) = r;
}

// ============ node update from normalized agg (agg lives in d_out) ==========
__global__ __launch_bounds__(256, 2)
void node_update_agg_kernel(const float* __restrict__ nf,
                            const float* __restrict__ aggin,   // == out (read own rows first)
                            const float* __restrict__ uw1,
                            const float* __restrict__ ub1,
                            const float* __restrict__ uw2,
                            const float* __restrict__ ub2,
                            float* __restrict__ out)
{
    __shared__ __align__(16) ushort sAct[WPB][32][UPD_LD];
    __shared__ __align__(16) ushort sW1t[64][UPD_LD];
    __shared__ __align__(16) ushort sW2t[64][H_LD];
    __shared__ float sUB1[64], sUB2[64];

    const int tid = threadIdx.x;
    const int w  = tid >> 6;
    const int l  = tid & 63;
    const int lr = l & 15;
    const int lg = l >> 4;

    {   // weight stage
        const int k16 = tid >> 4, n0 = (tid & 15) * 4;
        #pragma unroll
        for (int it = 0; it < 8; ++it) {
            const int k = k16 + 16 * it;
            const float4 v = *reinterpret_cast<const float4*>(uw1 + (size_t)k * HID + n0);
            sW1t[n0 + 0][k] = bf16r(v.x);
            sW1t[n0 + 1][k] = bf16r(v.y);
            sW1t[n0 + 2][k] = bf16r(v.z);
            sW1t[n0 + 3][k] = bf16r(v.w);
        }
        #pragma unroll
        for (int it = 0; it < 4; ++it) {
            const int k = k16 + 16 * it;
            const float4 v = *reinterpret_cast<const float4*>(uw2 + (size_t)k * ND + n0);
            sW2t[n0 + 0][k] = bf16r(v.x);
            sW2t[n0 + 1][k] = bf16r(v.y);
            sW2t[n0 + 2][k] = bf16r(v.z);
            sW2t[n0 + 3][k] = bf16r(v.w);
        }
        if (tid < 64) { sUB1[tid] = ub1[tid]; sUB2[tid] = ub2[tid]; }
    }

    const int nbase = blockIdx.x * 128 + w * 32;

    #pragma unroll
    for (int it = 0; it < 8; ++it) {
        const int row = lg + 4 * it;
        const int n = min(nbase + row, NN - 1);
        const float4 v = reinterpret_cast<const float4*>(nf + (size_t)n * ND)[lr];
        *reinterpret_cast<uint2*>(&sAct[w][row][lr * 4]) = pack4(v);
    }
    #pragma unroll
    for (int it = 0; it < 8; ++it) {
        const int row = lg + 4 * it;
        const int n = min(nbase + row, NN - 1);
        const float4 v = reinterpret_cast<const float4*>(aggin + (size_t)n * HID)[lr];
        *reinterpret_cast<uint2*>(&sAct[w][row][ND + lr * 4]) = pack4(v);
    }
    __syncthreads();

    short8 A[2][4];
    #pragma unroll
    for (int mt = 0; mt < 2; ++mt)
        #pragma unroll
        for (int ks = 0; ks < 4; ++ks)
            A[mt][ks] = *reinterpret_cast<const short8*>(&sAct[w][mt * 16 + lr][ks * 32 + 8 * lg]);
    #pragma unroll
    for (int nt = 0; nt < 4; ++nt) {
        const int cB = nt * 16 + lr;
        short8 B[4];
        #pragma unroll
        for (int ks = 0; ks < 4; ++ks)
            B[ks] = *reinterpret_cast<const short8*>(&sW1t[cB][ks * 32 + 8 * lg]);
        const float bv = sUB1[cB];
        #pragma unroll
        for (int mt = 0; mt < 2; ++mt) {
            f32x4 acc = (f32x4){bv, bv, bv, bv};
            #pragma unroll
            for (int ks = 0; ks < 4; ++ks)
                acc = __builtin_amdgcn_mfma_f32_16x16x32_bf16(A[mt][ks], B[ks], acc, 0, 0, 0);
            const int rH = mt * 16 + 4 * lg;
            #pragma unroll
            for (int r = 0; r < 4; ++r)
                sAct[w][rH + r][cB] = bf16r(fmaxf(acc[r], 0.0f));
        }
    }

    f32x4 o[2][4];
    #pragma unroll
    for (int nt = 0; nt < 4; ++nt) {
        const float v = sUB2[nt * 16 + lr];
        o[0][nt] = (f32x4){v, v, v, v};
        o[1][nt] = (f32x4){v, v, v, v};
    }
    #pragma unroll
    for (int mt = 0; mt < 2; ++mt) {
        const short8 A0 = *reinterpret_cast<const short8*>(&sAct[w][mt * 16 + lr][ 0 + 8 * lg]);
        const short8 A1 = *reinterpret_cast<const short8*>(&sAct[w][mt * 16 + lr][32 + 8 * lg]);
        #pragma unroll
        for (int nt = 0; nt < 4; ++nt) {
            const int cB = nt * 16 + lr;
            const short8 B0 = *reinterpret_cast<const short8*>(&sW2t[cB][ 0 + 8 * lg]);
            const short8 B1 = *reinterpret_cast<const short8*>(&sW2t[cB][32 + 8 * lg]);
            o[mt][nt] = __builtin_amdgcn_mfma_f32_16x16x32_bf16(A0, B0, o[mt][nt], 0, 0, 0);
            o[mt][nt] = __builtin_amdgcn_mfma_f32_16x16x32_bf16(A1, B1, o[mt][nt], 0, 0, 0);
        }
    }

    #pragma unroll
    for (int mt = 0; mt < 2; ++mt)
        #pragma unroll
        for (int r = 0; r < 4; ++r) {
            const int n = nbase + mt * 16 + 4 * lg + r;
            if (n < NN) {
                float* rowp = out + (size_t)n * ND;
                #pragma unroll
                for (int nt = 0; nt < 4; ++nt)
                    rowp[nt * 16 + lr] = o[mt][nt][r];
            }
        }
}

// ============== fallback node update (atomic-agg path, round-5) =============
__global__ __launch_bounds__(256, 2)
void node_update_kernel(const float* __restrict__ nf,
                        const float* __restrict__ agg,
                        const float* __restrict__ deg,
                        const float* __restrict__ uw1,
                        const float* __restrict__ ub1,
                        const float* __restrict__ uw2,
                        const float* __restrict__ ub2,
                        float* __restrict__ out)
{
    __shared__ __align__(16) ushort sAct[WPB][32][UPD_LD];
    __shared__ __align__(16) ushort sW1t[64][UPD_LD];
    __shared__ __align__(16) ushort sW2t[64][H_LD];
    __shared__ float sUB1[64], sUB2[64];

    const int tid = threadIdx.x;
    const int w  = tid >> 6;
    const int l  = tid & 63;
    const int lr = l & 15;
    const int lg = l >> 4;

    {
        const int k16 = tid >> 4, n0 = (tid & 15) * 4;
        #pragma unroll
        for (int it = 0; it < 8; ++it) {
            const int k = k16 + 16 * it;
            const float4 v = *reinterpret_cast<const float4*>(uw1 + (size_t)k * HID + n0);
            sW1t[n0 + 0][k] = bf16r(v.x);
            sW1t[n0 + 1][k] = bf16r(v.y);
            sW1t[n0 + 2][k] = bf16r(v.z);
            sW1t[n0 + 3][k] = bf16r(v.w);
        }
        #pragma unroll
        for (int it = 0; it < 4; ++it) {
            const int k = k16 + 16 * it;
            const float4 v = *reinterpret_cast<const float4*>(uw2 + (size_t)k * ND + n0);
            sW2t[n0 + 0][k] = bf16r(v.x);
            sW2t[n0 + 1][k] = bf16r(v.y);
            sW2t[n0 + 2][k] = bf16r(v.z);
            sW2t[n0 + 3][k] = bf16r(v.w);
        }
        if (tid < 64) { sUB1[tid] = ub1[tid]; sUB2[tid] = ub2[tid]; }
    }

    const int nbase = blockIdx.x * 128 + w * 32;
    float invv = 0.0f;
    if (l < 32) invv = 1.0f / (deg[min(nbase + l, NN - 1)] + 1e-8f);

    #pragma unroll
    for (int it = 0; it < 8; ++it) {
        const int row = lg + 4 * it;
        const int n = min(nbase + row, NN - 1);
        const float4 v = reinterpret_cast<const float4*>(nf + (size_t)n * ND)[lr];
        *reinterpret_cast<uint2*>(&sAct[w][row][lr * 4]) = pack4(v);
    }
    #pragma unroll
    for (int it = 0; it < 8; ++it) {
        const int row = lg + 4 * it;
        const int n = min(nbase + row, NN - 1);
        const float iv = __shfl(invv, row);
        float4 v = reinterpret_cast<const float4*>(agg + (size_t)n * HID)[lr];
        v.x *= iv; v.y *= iv; v.z *= iv; v.w *= iv;
        *reinterpret_cast<uint2*>(&sAct[w][row][ND + lr * 4]) = pack4(v);
    }
    __syncthreads();

    short8 A[2][4];
    #pragma unroll
    for (int mt = 0; mt < 2; ++mt)
        #pragma unroll
        for (int ks = 0; ks < 4; ++ks)
            A[mt][ks] = *reinterpret_cast<const short8*>(&sAct[w][mt * 16 + lr][ks * 32 + 8 * lg]);
    #pragma unroll
    for (int nt = 0; nt < 4; ++nt) {
        const int cB = nt * 16 + lr;
        short8 B[4];
        #pragma unroll
        for (int ks = 0; ks < 4; ++ks)
            B[ks] = *reinterpret_cast<const short8*>(&sW1t[cB][ks * 32 + 8 * lg]);
        const float bv = sUB1[cB];
        #pragma unroll
        for (int mt = 0; mt < 2; ++mt) {
            f32x4 acc = (f32x4){bv, bv, bv, bv};
            #pragma unroll
            for (int ks = 0; ks < 4; ++ks)
                acc = __builtin_amdgcn_mfma_f32_16x16x32_bf16(A[mt][ks], B[ks], acc, 0, 0, 0);
            const int rH = mt * 16 + 4 * lg;
            #pragma unroll
            for (int r = 0; r < 4; ++r)
                sAct[w][rH + r][cB] = bf16r(fmaxf(acc[r], 0.0f));
        }
    }

    f32x4 o[2][4];
    #pragma unroll
    for (int nt = 0; nt < 4; ++nt) {
        const float v = sUB2[nt * 16 + lr];
        o[0][nt] = (f32x4){v, v, v, v};
        o[1][nt] = (f32x4){v, v, v, v};
    }
    #pragma unroll
    for (int mt = 0; mt < 2; ++mt) {
        const short8 A0 = *reinterpret_cast<const short8*>(&sAct[w][mt * 16 + lr][ 0 + 8 * lg]);
        const short8 A1 = *reinterpret_cast<const short8*>(&sAct[w][mt * 16 + lr][32 + 8 * lg]);
        #pragma unroll
        for (int nt = 0; nt < 4; ++nt) {
            const int cB = nt * 16 + lr;
            const short8 B0 = *reinterpret_cast<const short8*>(&sW2t[cB][ 0 + 8 * lg]);
            const short8 B1 = *reinterpret_cast<const short8*>(&sW2t[cB][32 + 8 * lg]);
            o[mt][nt] = __builtin_amdgcn_mfma_f32_16x16x32_bf16(A0, B0, o[mt][nt], 0, 0, 0);
            o[mt][nt] = __builtin_amdgcn_mfma_f32_16x16x32_bf16(A1, B1, o[mt][nt], 0, 0, 0);
        }
    }

    #pragma unroll
    for (int mt = 0; mt < 2; ++mt)
        #pragma unroll
        for (int r = 0; r < 4; ++r) {
            const int n = nbase + mt * 16 + 4 * lg + r;
            if (n < NN) {
                float* rowp = out + (size_t)n * ND;
                #pragma unroll
                for (int nt = 0; nt < 4; ++nt)
                    rowp[nt * 16 + lr] = o[mt][nt][r];
            }
        }
}

extern "C" void kernel_launch(void* const* d_in, const int* in_sizes, int n_in,
                              void* d_out, int out_size, void* d_ws, size_t ws_size,
                              hipStream_t stream)
{
    const float* nf  = (const float*)d_in[0];
    const float* ef  = (const float*)d_in[1];
    const float* w1  = (const float*)d_in[2];
    const float* b1  = (const float*)d_in[3];
    const float* w2  = (const float*)d_in[4];
    const float* b2  = (const float*)d_in[5];
    const float* uw1 = (const float*)d_in[6];
    const float* ub1 = (const float*)d_in[7];
    const float* uw2 = (const float*)d_in[8];
    const float* ub2 = (const float*)d_in[9];
    const int*   src = (const int*)d_in[10];
    const int*   dst = (const int*)d_in[11];
    float* out = (float*)d_out;

    constexpr size_t MSGB  = (size_t)NE * 64 * 2;      // 102,400,000
    constexpr size_t PERMB = (size_t)NE * 4;           //   3,200,000
    constexpr size_t OFFB  = 200016;                   // (NN+1)*4 padded
    constexpr size_t CNTB  = (size_t)NN * 4;           //     200,000
    constexpr size_t BSUMB = 1024;                     // 196*4 padded
    constexpr size_t NEED  = MSGB + PERMB + OFFB + CNTB + BSUMB;

    if (ws_size >= NEED) {
        ushort* msgbuf = (ushort*)d_ws;
        int* perm = (int*)((char*)d_ws + MSGB);
        int* off  = (int*)((char*)d_ws + MSGB + PERMB);
        int* cnt  = (int*)((char*)d_ws + MSGB + PERMB + OFFB);   // later: cursor
        int* bsum = (int*)((char*)d_ws + MSGB + PERMB + OFFB + CNTB);

        (void)hipMemsetAsync(cnt, 0, CNTB, stream);
        hist_kernel<<<NE / 256, 256, 0, stream>>>(dst, cnt);
        scanA_kernel<<<NB_SCAN, 256, 0, stream>>>(cnt, off, bsum);
        scanB_kernel<<<1, 256, 0, stream>>>(bsum);
        scanC_kernel<<<NB_SCAN, 256, 0, stream>>>(bsum, off, cnt);
        fill_kernel<<<NE / 256, 256, 0, stream>>>(dst, cnt, perm);
        msg_kernel<1><<<NBLK, 256, 0, stream>>>(nf, ef, w1, b1, w2, b2, src, dst,
                                                msgbuf, nullptr, nullptr);
        gather_kernel<<<NN / 16, 256, 0, stream>>>(msgbuf, perm, off, out);
        node_update_agg_kernel<<<(NN + 127) / 128, 256, 0, stream>>>(
            nf, out, uw1, ub1, uw2, ub2, out);
    } else {
        float* agg = (float*)d_ws;                    // [NN][HID]
        float* deg = agg + (size_t)NN * HID;          // [NN]
        (void)hipMemsetAsync(d_ws, 0, ((size_t)NN * HID + NN) * sizeof(float), stream);
        msg_kernel<0><<<NBLK, 256, 0, stream>>>(nf, ef, w1, b1, w2, b2, src, dst,
                                                nullptr, agg, deg);
        node_update_kernel<<<(NN + 127) / 128, 256, 0, stream>>>(nf, agg, deg,
                                                                 uw1, ub1, uw2, ub2, out);
    }
}